// Round 11
// baseline (281.119 us; speedup 1.0000x reference)
//
#include <hip/hip_runtime.h>
#include <cstdint>
#include <cstddef>

// KAN layer: out[b,j] = sum_{i,k} basis_k(tanh x[b,i]) * C[j,i,k]
// basis is 2-sparse (adjacent slots lo, lo+1), support slots 0..11.
// R22: GEMM = R19's kan_gemm13 VERBATIM (best measured: 112us; BM 64,
// wave 32x64, KSPL2=2, ring-4 Bs + ring-2 As, vmcnt(3)). R13-R21
// exonerated every gemm-side lever (schedule/occupancy/atomics/padding/
// conflicts/tile shape: all 112-140us). The constant ~70us total-vs-gemm
// gap across ALL rounds (invariant to dispatch count) is prep+reduce+
// fixed cost -> attack that: (1) reduce dispatch ELIMINATED: per-m-tile
// ticket (atomicAdd) in ws; second-finishing block sums p0+p1 -> out
// (fence+barrier+device-atomic handoff; all 256 blocks resident).
// (2) prep_B2 rewritten LDS-staged: coalesced float4 loads (26.6KB/block),
// records read from LDS (stride-13 words, conflict-spread), coalesced
// 24B-record writes; also zeroes the 128 tickets.

typedef _Float16 half2_v __attribute__((ext_vector_type(2)));
typedef __fp16  fp16x2  __attribute__((ext_vector_type(2)));
typedef _Float16 f16x8 __attribute__((ext_vector_type(8)));
typedef float f32x4 __attribute__((ext_vector_type(4)));

__device__ __forceinline__ half2_v u32_as_h2(uint32_t u) {
  union { uint32_t u; half2_v h; } c; c.u = u; return c.h;
}
__device__ __forceinline__ uint32_t h2_as_u32(half2_v h) {
  union { uint32_t u; half2_v h; } c; c.h = h; return c.u;
}
__device__ __forceinline__ half2_v cvt_pk_h2(float a, float b) {
  union { fp16x2 f; half2_v h; } c;
  c.f = __builtin_amdgcn_cvt_pkrtz(a, b);
  return c.h;
}
__device__ __forceinline__ float dot2f(half2_v a, half2_v b, float c) {
#if __has_builtin(__builtin_amdgcn_fdot2)
  return __builtin_amdgcn_fdot2(a, b, c, false);
#else
  return c + (float)a[0] * (float)b[0] + (float)a[1] * (float)b[1];
#endif
}
__device__ __forceinline__ uint16_t f16_bits(float v) {
  union { _Float16 h; uint16_t u; } c; c.h = (_Float16)v; return c.u;
}

__device__ __forceinline__ float fast_tanhf(float v) {
  const float e = __expf(2.0f * v);
  return 1.0f - 2.0f / (e + 1.0f);
}

// ---- basis-weight computation (analytic uniform knots; verified R10) ----
#define KSTEP 0.13333333333333333f
#define KINV  7.49999943750004f      // 1/(2/15 + 1e-8)
__device__ __forceinline__ void kan_weights(float xin, float& w0, float& w1, int& lo) {
  float xc = fast_tanhf(xin);
  xc = fminf(fmaxf(xc, -1.0f), 1.0f);
  int m = (int)((xc + 1.0f) * 7.5f);   // interval index; basis continuity makes +-1 ULP safe
  m = min(max(m, 0), 14);
  const float k0 = fmaf((float)m, KSTEP, -1.0f);
  const float up = (xc - k0) * KINV;
  const float dn = (k0 + KSTEP - xc) * KINV;
  // m==0: up on slot 0 | 1<=m<=11: dn on m-1, up on m | m==12: dn on 11 | m>=13: zero
  w0 = (m == 0) ? up : ((m <= 12) ? dn : 0.0f);
  w1 = (m >= 1 && m <= 11) ? up : 0.0f;
  lo = min(max(m - 1, 0), 11);
}

__device__ __forceinline__ void load_lds16(const void* g, void* l) {
  __builtin_amdgcn_global_load_lds((const __attribute__((address_space(1))) void*)g,
                                   (__attribute__((address_space(3))) void*)l, 16, 0, 0);
}

// ================= fast path =================
#define GMM 8192
#define GNN 256
#define KI  12                 // slots per i (true support)
#define GK2 (1024 * KI)        // 12288 f16 per B2 row
#define KSPL2 2
#define IPER (1024 / KSPL2)    // 512 i per split
#define BM2 64
#define BN2 256
#define NSG 64                 // super-granules per block (8 i each)
#define NSTEP 192              // K-steps per block (3 per sg)
#define AS_STRIDE 208          // 192 B data + 16 B pad (13 words: odd -> bank spread)
#define AS_SG (64 * AS_STRIDE) // 13312 B
#define OUT_ELEMS (8192 * 256)

// prep_B2: f16 B2[j][i*12+s], s=0..11 from coef. LDS-staged so both global
// sides are coalesced. Zeroes tickets (partial path) / out (atomic path).
__global__ __launch_bounds__(512)
void kan_prep_B2(const float* __restrict__ coef, uint32_t* __restrict__ B2,
                 float4* __restrict__ outz, unsigned* __restrict__ ticket,
                 int zero_out) {
  __shared__ float Cl[512 * 13];                    // 26624 B
  const int t    = threadIdx.x;
  const int rec0 = blockIdx.x * 512;
  // coalesced stage: 512*52 B = 1664 float4 (base 26624*blockIdx: 16B-aligned)
  const float4* src = (const float4*)(coef + (size_t)rec0 * 13);
  float4* dl = (float4*)Cl;
  dl[t]        = src[t];
  dl[t + 512]  = src[t + 512];
  dl[t + 1024] = src[t + 1024];
  if (t < 128) dl[t + 1536] = src[t + 1536];
  __syncthreads();
  const float* cp = Cl + t * 13;                    // stride 13 words: bank-spread
  uint32_t w[6];
#pragma unroll
  for (int q = 0; q < 6; ++q) w[q] = h2_as_u32(cvt_pk_h2(cp[2 * q], cp[2 * q + 1]));
  uint2* p = (uint2*)(B2 + (size_t)(rec0 + t) * 6); // 24 B per (j,i), 8B aligned
  p[0] = make_uint2(w[0], w[1]);
  p[1] = make_uint2(w[2], w[3]);
  p[2] = make_uint2(w[4], w[5]);
  if (zero_out) {                                   // atomic path: zero out[]
    const float4 z = make_float4(0.f, 0.f, 0.f, 0.f);
    outz[blockIdx.x * 1024 + t] = z;
    outz[blockIdx.x * 1024 + 512 + t] = z;
  }
  if (ticket != nullptr && blockIdx.x == 0 && t < 128) ticket[t] = 0u;
}

__global__ __launch_bounds__(512, 2)
void kan_gemm16(const float* __restrict__ x, const _Float16* __restrict__ B2,
                float* __restrict__ out, float* __restrict__ part,
                unsigned* __restrict__ ticket, int mode) {
  // Bs: ring-4 K-step buffers [256 j][64 B], chunk-swizzled (LDS chunk c
  //     holds global chunk c ^ (row&3)).
  // As: ring-2 super-granule buffers [64 rows][8 i x 24 B + 16 pad].
  __shared__ __align__(16) char Bs[4][16384];
  __shared__ __align__(16) char As[2][AS_SG];
  __shared__ unsigned s_flag;
  char* BsP = (char*)Bs;
  char* AsP = (char*)As;

  const int t    = threadIdx.x;
  const int lane = t & 63;
  const int wv   = t >> 6;          // 0..7
  const int wm   = (wv & 1) * 32;   // wave m-offset (of 64)
  const int wn   = (wv >> 1) * 64;  // wave n-offset (of 256)
  const int fr   = lane & 15;
  const int fq   = lane >> 4;
  const int m0   = blockIdx.z * BM2;   // m on z
  const int i00  = blockIdx.x * IPER;  // i-split on x

  // frag bases
  const int a_base = (wm + fr) * AS_STRIDE + fq * 16;
  const int b_base = (wn + fr) * 64 + ((fq ^ (fr & 3)) * 16);

  f32x4 acc[2][4];
#pragma unroll
  for (int a = 0; a < 2; ++a)
#pragma unroll
    for (int b = 0; b < 4; ++b) acc[a][b] = (f32x4){0.f, 0.f, 0.f, 0.f};

  // B staging: per K-step tile [256 j][64 B] = 1024 x 16B chunks; thread t
  // owns {t, 512+t}: row = n>>2, LDS chunk sc holds global chunk sc^(row&3).
  const int srow0 = t >> 2, sc0 = t & 3;
  const int srow1 = 128 + (t >> 2);
  const _Float16* sp0 = B2 + (size_t)srow0 * GK2 + (size_t)i00 * KI
                        + ((sc0 ^ (srow0 & 3)) * 8);
  const _Float16* sp1 = B2 + (size_t)srow1 * GK2 + (size_t)i00 * KI
                        + ((sc0 ^ (srow1 & 3)) * 8);
  // per K-step advance: 32 f16 = 64 B.

  // expand mapping: thread t -> (row = t&63, i_loc = t>>6 in 0..7) — one
  // item per sg. i_loc == wave id (wave-uniform).
  const int xrow  = t & 63;
  const int i_loc = t >> 6;
  const float* xptr = x + (size_t)(m0 + xrow) * 1024 + i00 + i_loc;
  const int exp_off = xrow * AS_STRIDE + i_loc * 24;

  auto expand1 = [&](int dst, float xv) {
    float w0, w1; int lo;
    kan_weights(xv, w0, w1, lo);
    const uint32_t wp  = (uint32_t)f16_bits(w0) | ((uint32_t)f16_bits(w1) << 16);
    const uint32_t wlo = (lo & 1) ? (wp << 16) : wp;
    const uint32_t whi = (lo & 1) ? (wp >> 16) : 0u;
    const int w   = lo >> 1;                       // word 0..5
    const int wn1 = (w + 1 > 5) ? 5 : (w + 1);     // clamp: lo=11 => w1==0
    char* rb = AsP + dst + exp_off;
    if ((i_loc & 1) == 0) {                        // wave-uniform branch
      *(uint4*)(rb)      = make_uint4(0u, 0u, 0u, 0u);
      *(uint2*)(rb + 16) = make_uint2(0u, 0u);
    } else {
      *(uint2*)(rb)      = make_uint2(0u, 0u);
      *(uint4*)(rb + 8)  = make_uint4(0u, 0u, 0u, 0u);
    }
    *(uint32_t*)(rb + wn1 * 4) = whi;              // order: whi then wlo
    *(uint32_t*)(rb + w * 4)   = wlo;              // (same-word clamp: wlo wins)
  };

  float cx, nx = 0.f;

  // ---- prologue: expand sg0 -> As[0]; stage step0->slot0, step1->slot1 ----
  {
    const float ex = xptr[0];
    load_lds16(sp0, BsP + t * 16);
    load_lds16(sp1, BsP + 8192 + t * 16);
    sp0 += 32; sp1 += 32;
    load_lds16(sp0, BsP + 16384 + t * 16);
    load_lds16(sp1, BsP + 16384 + 8192 + t * 16);
    sp0 += 32; sp1 += 32;
    expand1(0, ex);
    cx = xptr[8];                     // x(sg1)
  }
  // vmcnt(2): of the 5 possibly-outstanding vmem ops, allow only the 2
  // newest -> step0's pair complete regardless of compiler interleave.
  asm volatile("s_waitcnt vmcnt(2) lgkmcnt(0)" ::: "memory");
  __builtin_amdgcn_s_barrier();
  __builtin_amdgcn_sched_barrier(0);

// Phase = one K-step (global g = 12B + 3U + PH, slot (3U+PH)&3). Reads
// As[U&1] slice PH; stages step g+2 -> slot (3U+PH+2)&3; expands sg+1 into
// As[(U+1)&1] at PH0; counted wait vmcnt(3) (the 3 newest = stage(g+2) x2
// + at most 1 x prefetch -> stage(g+1) forced complete); barrier; 8 MFMA.
#define GRANP(U, PH, XPF)                                                     \
  {                                                                           \
    const int g = 12 * B + 3 * (U) + (PH);                                    \
    const char* Asrc = AsP + ((U) & 1) * AS_SG;                               \
    f16x8 af0 = *(const f16x8*)(Asrc + a_base + (PH) * 64);                   \
    f16x8 af1 = *(const f16x8*)(Asrc + a_base + (PH) * 64 + 16 * AS_STRIDE);  \
    load_lds16(sp0, BsP + ((3 * (U) + (PH) + 2) & 3) * 16384 + t * 16);       \
    load_lds16(sp1, BsP + ((3 * (U) + (PH) + 2) & 3) * 16384 + 8192 + t * 16);\
    { const int adv = (g + 3 <= NSTEP - 1) ? 32 : 0; sp0 += adv; sp1 += adv; }\
    XPF                                                                       \
    if ((PH) == 0 && (4 * B + (U)) < NSG - 1)                                 \
      expand1((((U) + 1) & 1) * AS_SG, cx);                                   \
    asm volatile("s_waitcnt vmcnt(3) lgkmcnt(0)" ::: "memory");               \
    __builtin_amdgcn_s_barrier();                                             \
    __builtin_amdgcn_sched_barrier(0);                                        \
    __builtin_amdgcn_s_setprio(1);                                            \
    _Pragma("unroll")                                                         \
    for (int ni = 0; ni < 4; ++ni) {                                          \
      const f16x8 bf = *(const f16x8*)(BsP + ((3 * (U) + (PH)) & 3) * 16384   \
                                       + b_base + ni * 1024);                 \
      acc[0][ni] = __builtin_amdgcn_mfma_f32_16x16x32_f16(af0, bf, acc[0][ni], 0, 0, 0); \
      acc[1][ni] = __builtin_amdgcn_mfma_f32_16x16x32_f16(af1, bf, acc[1][ni], 0, 0, 0); \
    }                                                                         \
    __builtin_amdgcn_s_setprio(0);                                            \
  }

#define SGBODY(U)                                                             \
  {                                                                           \
    const int sgp = 4 * B + (U) + 2;                                          \
    const int sgn = (sgp < NSG) ? sgp : (NSG - 1);                            \
    GRANP(U, 0, { })                                                          \
    GRANP(U, 1, { nx = xptr[8 * sgn]; })                                      \
    GRANP(U, 2, { })                                                          \
    cx = nx;                                                                  \
  }

  for (int B = 0; B < 16; ++B) {
    SGBODY(0)
    SGBODY(1)
    SGBODY(2)
    SGBODY(3)
  }
#undef SGBODY
#undef GRANP

  if (mode) {
    // partial-sum path: plain stores into part[s][b][j]; then per-m-tile
    // ticket -- the SECOND finisher sums p0+p1 into out (no reduce kernel).
    float* pb = part + (size_t)blockIdx.x * OUT_ELEMS;
#pragma unroll
    for (int q = 0; q < 2; ++q) {
      const int gr = m0 + wm + q * 16 + fq * 4;
#pragma unroll
      for (int ni = 0; ni < 4; ++ni) {
        const int gc = wn + ni * 16 + fr;
#pragma unroll
        for (int r = 0; r < 4; ++r)
          pb[(size_t)(gr + r) * GNN + gc] = acc[q][ni][r];
      }
    }
    __threadfence();                 // make this thread's partial stores
    __syncthreads();                 // device-visible; all threads fenced
    if (t == 0) s_flag = atomicAdd(&ticket[blockIdx.z], 1u);
    __syncthreads();
    if (s_flag == 1u) {              // we are the second finisher for tile z
      __threadfence();               // acquire: see the other block's stores
      const float4* p0 = (const float4*)part + (size_t)m0 * 64;
      const float4* p1 = (const float4*)(part + OUT_ELEMS) + (size_t)m0 * 64;
      float4* ob = (float4*)out + (size_t)m0 * 64;
#pragma unroll
      for (int q = 0; q < 8; ++q) {  // 64 rows x 256 cols = 4096 float4
        const int idx = q * 512 + t;
        const float4 a = p0[idx];
        const float4 b = p1[idx];
        ob[idx] = make_float4(a.x + b.x, a.y + b.y, a.z + b.z, a.w + b.w);
      }
    }
  } else {
#pragma unroll
    for (int q = 0; q < 2; ++q) {
      const int gr = m0 + wm + q * 16 + fq * 4;
#pragma unroll
      for (int ni = 0; ni < 4; ++ni) {
        const int gc = wn + ni * 16 + fr;
#pragma unroll
        for (int r = 0; r < 4; ++r)
          atomicAdd(&out[(size_t)(gr + r) * GNN + gc], acc[q][ni][r]);
      }
    }
  }
}

// ================= fallback: direct dot2 path (no workspace) =================
#define TI 8
#define BT 256
#define JT 32
#define ISPL 2
#define IRANGE (1024 / ISPL)

__global__ __launch_bounds__(256)
void kan_dot2(const float* __restrict__ x, const float* __restrict__ coef,
              float* __restrict__ out) {
  __shared__ uint32_t Plds[TI * 12 * JT];
  const int t    = threadIdx.x;
  const int b    = blockIdx.x * BT + t;
  const int j0   = blockIdx.y * JT;
  const int cbeg = blockIdx.z * (IRANGE / TI);

  float acc[JT];
#pragma unroll
  for (int q = 0; q < JT; ++q) acc[q] = 0.0f;

  const int s_jj   = t & 31;
  const int s_iloc = t >> 5;

  for (int c = cbeg; c < cbeg + IRANGE / TI; ++c) {
    const int i0 = c * TI;
    __syncthreads();
    {
      const float* cp0 = coef + ((size_t)(j0 + s_jj) * 1024 + (i0 + s_iloc)) * 13;
      float cv[13];
#pragma unroll
      for (int s = 0; s < 13; ++s) cv[s] = cp0[s];
#pragma unroll
      for (int r = 0; r < 12; ++r) {
        half2_v h; h[0] = (_Float16)cv[r]; h[1] = (_Float16)cv[r + 1];
        const int slot = ((s_jj >> 2) + r) & 7;
        Plds[(s_iloc * 12 + r) * 32 + slot * 4 + (s_jj & 3)] = h2_as_u32(h);
      }
    }
    uint32_t wr[TI]; int lor[TI];
    {
      const float* xr = x + (size_t)b * 1024 + i0;
      const float4 xa = *(const float4*)(xr);
      const float4 xb = *(const float4*)(xr + 4);
      const float xv[TI] = {xa.x, xa.y, xa.z, xa.w, xb.x, xb.y, xb.z, xb.w};
#pragma unroll
      for (int q = 0; q < TI; ++q) {
        float w0, w1; int lo;
        kan_weights(xv[q], w0, w1, lo);
        wr[q] = (uint32_t)f16_bits(w0) | ((uint32_t)f16_bits(w1) << 16);
        lor[q] = lo;
      }
    }
    __syncthreads();

    const uint4* P4 = (const uint4*)Plds;
#pragma unroll
    for (int ii = 0; ii < TI; ++ii) {
      const half2_v hw = u32_as_h2(wr[ii]);
      const int lo = lor[ii];
      const int base = (ii * 12 + lo) * 8;
#pragma unroll
      for (int g = 0; g < 8; ++g) {
        const uint4 v = P4[base + ((g + lo) & 7)];
        acc[4 * g + 0] = dot2f(hw, u32_as_h2(v.x), acc[4 * g + 0]);
        acc[4 * g + 1] = dot2f(hw, u32_as_h2(v.y), acc[4 * g + 1]);
        acc[4 * g + 2] = dot2f(hw, u32_as_h2(v.z), acc[4 * g + 2]);
        acc[4 * g + 3] = dot2f(hw, u32_as_h2(v.w), acc[4 * g + 3]);
      }
    }
  }

  float* orow = out + (size_t)b * 256 + j0;
#pragma unroll
  for (int q = 0; q < JT; ++q) atomicAdd(orow + q, acc[q]);
}

extern "C" void kernel_launch(void* const* d_in, const int* in_sizes, int n_in,
                              void* d_out, int out_size, void* d_ws, size_t ws_size,
                              hipStream_t stream) {
  const float* x     = (const float*)d_in[0];
  const float* coef  = (const float*)d_in[1];
  float* out = (float*)d_out;

  const size_t b2_bytes   = (size_t)GNN * GK2 * 2;           // 6.29 MB
  const size_t part_off   = b2_bytes;                        // 16-B aligned
  const size_t part_bytes = (size_t)KSPL2 * OUT_ELEMS * 4;   // 16.8 MB
  const size_t tick_off   = part_off + part_bytes;
  const size_t tick_bytes = 128 * sizeof(unsigned);

  if (ws_size >= tick_off + tick_bytes) {
    // no-atomic path: partials + in-gemm ticket reduction (2 dispatches)
    _Float16* B2 = (_Float16*)d_ws;
    float* part  = (float*)((char*)d_ws + part_off);
    unsigned* tk = (unsigned*)((char*)d_ws + tick_off);
    kan_prep_B2<<<512, 512, 0, stream>>>(coef, (uint32_t*)B2, (float4*)out, tk, 0);
    dim3 grid(KSPL2, 1, GMM / BM2);                          // (2, 1, 128) = 256
    kan_gemm16<<<grid, 512, 0, stream>>>(x, B2, out, part, tk, 1);
  } else if (ws_size >= b2_bytes) {
    // atomic path (16 MB of atomics)
    _Float16* B2 = (_Float16*)d_ws;
    kan_prep_B2<<<512, 512, 0, stream>>>(coef, (uint32_t*)B2, (float4*)out,
                                         nullptr, 1);
    dim3 grid(KSPL2, 1, GMM / BM2);
    kan_gemm16<<<grid, 512, 0, stream>>>(x, B2, out, nullptr, nullptr, 0);
  } else {
    (void)hipMemsetAsync(out, 0, (size_t)out_size * sizeof(float), stream);
    dim3 grid(8192 / BT, 256 / JT, ISPL);
    kan_dot2<<<grid, 256, 0, stream>>>(x, coef, out);
  }
}

// Round 12
// 187.847 us; speedup vs baseline: 1.4965x; 1.4965x over previous
//
#include <hip/hip_runtime.h>
#include <cstdint>
#include <cstddef>

// KAN layer: out[b,j] = sum_{i,k} basis_k(tanh x[b,i]) * C[j,i,k]
// basis is 2-sparse (adjacent slots lo, lo+1), support slots 0..11.
// R23: RESTORE R19 (measured optimum: gemm 112us, total 187.5us) + the one
// independently-verified R22 piece: LDS-staged coalesced prep_B2.
// R13-R22 exonerated every lever: schedule (R15), drain (R16), occupancy
// (R16/R20), atomics (R17/R19), K-pad (R18), conflicts/stride (R21), tile
// shape (R13/R20/R21), fused reduction (R22: threadfence+ticket = +100us).
// Sparse-dot2 reformulation has an 8.6GB LDS-gather floor (~125us) - no
// cheaper algorithm. Gemm = kan_gemm13 verbatim (BM 64, wave 32x64,
// KSPL2=2, ring-4 Bs vmcnt(3), ring-2 As, partial stores); separate
// reduce2; prep reads/writes fully coalesced via 26.6KB LDS stage.

typedef _Float16 half2_v __attribute__((ext_vector_type(2)));
typedef __fp16  fp16x2  __attribute__((ext_vector_type(2)));
typedef _Float16 f16x8 __attribute__((ext_vector_type(8)));
typedef float f32x4 __attribute__((ext_vector_type(4)));

__device__ __forceinline__ half2_v u32_as_h2(uint32_t u) {
  union { uint32_t u; half2_v h; } c; c.u = u; return c.h;
}
__device__ __forceinline__ uint32_t h2_as_u32(half2_v h) {
  union { uint32_t u; half2_v h; } c; c.h = h; return c.u;
}
__device__ __forceinline__ half2_v cvt_pk_h2(float a, float b) {
  union { fp16x2 f; half2_v h; } c;
  c.f = __builtin_amdgcn_cvt_pkrtz(a, b);
  return c.h;
}
__device__ __forceinline__ float dot2f(half2_v a, half2_v b, float c) {
#if __has_builtin(__builtin_amdgcn_fdot2)
  return __builtin_amdgcn_fdot2(a, b, c, false);
#else
  return c + (float)a[0] * (float)b[0] + (float)a[1] * (float)b[1];
#endif
}
__device__ __forceinline__ uint16_t f16_bits(float v) {
  union { _Float16 h; uint16_t u; } c; c.h = (_Float16)v; return c.u;
}

__device__ __forceinline__ float fast_tanhf(float v) {
  const float e = __expf(2.0f * v);
  return 1.0f - 2.0f / (e + 1.0f);
}

// ---- basis-weight computation (analytic uniform knots; verified R10) ----
#define KSTEP 0.13333333333333333f
#define KINV  7.49999943750004f      // 1/(2/15 + 1e-8)
__device__ __forceinline__ void kan_weights(float xin, float& w0, float& w1, int& lo) {
  float xc = fast_tanhf(xin);
  xc = fminf(fmaxf(xc, -1.0f), 1.0f);
  int m = (int)((xc + 1.0f) * 7.5f);   // interval index; basis continuity makes +-1 ULP safe
  m = min(max(m, 0), 14);
  const float k0 = fmaf((float)m, KSTEP, -1.0f);
  const float up = (xc - k0) * KINV;
  const float dn = (k0 + KSTEP - xc) * KINV;
  // m==0: up on slot 0 | 1<=m<=11: dn on m-1, up on m | m==12: dn on 11 | m>=13: zero
  w0 = (m == 0) ? up : ((m <= 12) ? dn : 0.0f);
  w1 = (m >= 1 && m <= 11) ? up : 0.0f;
  lo = min(max(m - 1, 0), 11);
}

__device__ __forceinline__ void load_lds16(const void* g, void* l) {
  __builtin_amdgcn_global_load_lds((const __attribute__((address_space(1))) void*)g,
                                   (__attribute__((address_space(3))) void*)l, 16, 0, 0);
}

// ================= fast path =================
#define GMM 8192
#define GNN 256
#define KI  12                 // slots per i (true support)
#define GK2 (1024 * KI)        // 12288 f16 per B2 row
#define KSPL2 2
#define IPER (1024 / KSPL2)    // 512 i per split
#define BM2 64
#define BN2 256
#define NSG 64                 // super-granules per block (8 i each)
#define NSTEP 192              // K-steps per block (3 per sg)
#define AS_STRIDE 208          // 192 B data + 16 B pad (13 words: odd -> bank spread)
#define AS_SG (64 * AS_STRIDE) // 13312 B
#define OUT_ELEMS (8192 * 256)

// prep_B2: f16 B2[j][i*12+s], s=0..11 from coef. LDS-staged so both global
// sides are coalesced (verified in R22). Zeroes out[] for the atomic path.
__global__ __launch_bounds__(512)
void kan_prep_B2(const float* __restrict__ coef, uint32_t* __restrict__ B2,
                 float4* __restrict__ outz, int zero_out) {
  __shared__ float Cl[512 * 13];                    // 26624 B
  const int t    = threadIdx.x;
  const int rec0 = blockIdx.x * 512;
  // coalesced stage: 512*52 B = 1664 float4 (base 26624*blockIdx: 16B-aligned)
  const float4* src = (const float4*)(coef + (size_t)rec0 * 13);
  float4* dl = (float4*)Cl;
  dl[t]        = src[t];
  dl[t + 512]  = src[t + 512];
  dl[t + 1024] = src[t + 1024];
  if (t < 128) dl[t + 1536] = src[t + 1536];
  __syncthreads();
  const float* cp = Cl + t * 13;                    // stride 13 words: bank-spread
  uint32_t w[6];
#pragma unroll
  for (int q = 0; q < 6; ++q) w[q] = h2_as_u32(cvt_pk_h2(cp[2 * q], cp[2 * q + 1]));
  uint2* p = (uint2*)(B2 + (size_t)(rec0 + t) * 6); // 24 B per (j,i)
  p[0] = make_uint2(w[0], w[1]);
  p[1] = make_uint2(w[2], w[3]);
  p[2] = make_uint2(w[4], w[5]);
  if (zero_out) {                                   // atomic path: zero out[]
    const float4 z = make_float4(0.f, 0.f, 0.f, 0.f);
    outz[blockIdx.x * 1024 + t] = z;
    outz[blockIdx.x * 1024 + 512 + t] = z;
  }
}

// reduce: out = part[0] + part[1] (partial-sum path)
__global__ __launch_bounds__(256)
void kan_reduce2(const float4* __restrict__ part, float4* __restrict__ out) {
  const int i = blockIdx.x * 256 + threadIdx.x;     // 524288 float4
  out[i] = make_float4(part[i].x + part[i + OUT_ELEMS / 4].x,
                       part[i].y + part[i + OUT_ELEMS / 4].y,
                       part[i].z + part[i + OUT_ELEMS / 4].z,
                       part[i].w + part[i + OUT_ELEMS / 4].w);
}

__global__ __launch_bounds__(512, 2)
void kan_gemm13(const float* __restrict__ x, const _Float16* __restrict__ B2,
                float* __restrict__ out, float* __restrict__ part, int mode) {
  // Bs: ring-4 K-step buffers [256 j][64 B], chunk-swizzled (LDS chunk c
  //     holds global chunk c ^ (row&3)).
  // As: ring-2 super-granule buffers [64 rows][8 i x 24 B + 16 pad].
  __shared__ __align__(16) char Bs[4][16384];
  __shared__ __align__(16) char As[2][AS_SG];
  char* BsP = (char*)Bs;
  char* AsP = (char*)As;

  const int t    = threadIdx.x;
  const int lane = t & 63;
  const int wv   = t >> 6;          // 0..7
  const int wm   = (wv & 1) * 32;   // wave m-offset (of 64)
  const int wn   = (wv >> 1) * 64;  // wave n-offset (of 256)
  const int fr   = lane & 15;
  const int fq   = lane >> 4;
  const int m0   = blockIdx.z * BM2;   // m on z
  const int i00  = blockIdx.x * IPER;  // i-split on x; linear = s+2m -> XCD parity = s

  // frag bases
  const int a_base = (wm + fr) * AS_STRIDE + fq * 16;
  const int b_base = (wn + fr) * 64 + ((fq ^ (fr & 3)) * 16);

  f32x4 acc[2][4];
#pragma unroll
  for (int a = 0; a < 2; ++a)
#pragma unroll
    for (int b = 0; b < 4; ++b) acc[a][b] = (f32x4){0.f, 0.f, 0.f, 0.f};

  // B staging: per K-step tile [256 j][64 B] = 1024 x 16B chunks; thread t
  // owns {t, 512+t}: row = n>>2, LDS chunk sc holds global chunk sc^(row&3).
  const int srow0 = t >> 2, sc0 = t & 3;
  const int srow1 = 128 + (t >> 2);
  const _Float16* sp0 = B2 + (size_t)srow0 * GK2 + (size_t)i00 * KI
                        + ((sc0 ^ (srow0 & 3)) * 8);
  const _Float16* sp1 = B2 + (size_t)srow1 * GK2 + (size_t)i00 * KI
                        + ((sc0 ^ (srow1 & 3)) * 8);
  // per K-step advance: 32 f16 = 64 B.

  // expand mapping: thread t -> (row = t&63, i_loc = t>>6 in 0..7) — one
  // item per sg. i_loc == wave id (wave-uniform).
  const int xrow  = t & 63;
  const int i_loc = t >> 6;
  const float* xptr = x + (size_t)(m0 + xrow) * 1024 + i00 + i_loc;
  const int exp_off = xrow * AS_STRIDE + i_loc * 24;

  auto expand1 = [&](int dst, float xv) {
    float w0, w1; int lo;
    kan_weights(xv, w0, w1, lo);
    const uint32_t wp  = (uint32_t)f16_bits(w0) | ((uint32_t)f16_bits(w1) << 16);
    const uint32_t wlo = (lo & 1) ? (wp << 16) : wp;
    const uint32_t whi = (lo & 1) ? (wp >> 16) : 0u;
    const int w   = lo >> 1;                       // word 0..5
    const int wn1 = (w + 1 > 5) ? 5 : (w + 1);     // clamp: lo=11 => w1==0
    char* rb = AsP + dst + exp_off;
    if ((i_loc & 1) == 0) {                        // wave-uniform branch
      *(uint4*)(rb)      = make_uint4(0u, 0u, 0u, 0u);
      *(uint2*)(rb + 16) = make_uint2(0u, 0u);
    } else {
      *(uint2*)(rb)      = make_uint2(0u, 0u);
      *(uint4*)(rb + 8)  = make_uint4(0u, 0u, 0u, 0u);
    }
    *(uint32_t*)(rb + wn1 * 4) = whi;              // order: whi then wlo
    *(uint32_t*)(rb + w * 4)   = wlo;              // (same-word clamp: wlo wins)
  };

  float cx, nx = 0.f;

  // ---- prologue: expand sg0 -> As[0]; stage step0->slot0, step1->slot1 ----
  {
    const float ex = xptr[0];
    load_lds16(sp0, BsP + t * 16);
    load_lds16(sp1, BsP + 8192 + t * 16);
    sp0 += 32; sp1 += 32;
    load_lds16(sp0, BsP + 16384 + t * 16);
    load_lds16(sp1, BsP + 16384 + 8192 + t * 16);
    sp0 += 32; sp1 += 32;
    expand1(0, ex);
    cx = xptr[8];                     // x(sg1)
  }
  // vmcnt(2): of the 5 possibly-outstanding vmem ops, allow only the 2
  // newest -> step0's pair complete regardless of compiler interleave.
  asm volatile("s_waitcnt vmcnt(2) lgkmcnt(0)" ::: "memory");
  __builtin_amdgcn_s_barrier();
  __builtin_amdgcn_sched_barrier(0);

// Phase = one K-step (global g = 12B + 3U + PH, slot (3U+PH)&3). Reads
// As[U&1] slice PH; stages step g+2 -> slot (3U+PH+2)&3; expands sg+1 into
// As[(U+1)&1] at PH0; counted wait vmcnt(3) (the 3 newest = stage(g+2) x2
// + at most 1 x prefetch -> stage(g+1) forced complete); barrier; 8 MFMA.
#define GRANP(U, PH, XPF)                                                     \
  {                                                                           \
    const int g = 12 * B + 3 * (U) + (PH);                                    \
    const char* Asrc = AsP + ((U) & 1) * AS_SG;                               \
    f16x8 af0 = *(const f16x8*)(Asrc + a_base + (PH) * 64);                   \
    f16x8 af1 = *(const f16x8*)(Asrc + a_base + (PH) * 64 + 16 * AS_STRIDE);  \
    load_lds16(sp0, BsP + ((3 * (U) + (PH) + 2) & 3) * 16384 + t * 16);       \
    load_lds16(sp1, BsP + ((3 * (U) + (PH) + 2) & 3) * 16384 + 8192 + t * 16);\
    { const int adv = (g + 3 <= NSTEP - 1) ? 32 : 0; sp0 += adv; sp1 += adv; }\
    XPF                                                                       \
    if ((PH) == 0 && (4 * B + (U)) < NSG - 1)                                 \
      expand1((((U) + 1) & 1) * AS_SG, cx);                                   \
    asm volatile("s_waitcnt vmcnt(3) lgkmcnt(0)" ::: "memory");               \
    __builtin_amdgcn_s_barrier();                                             \
    __builtin_amdgcn_sched_barrier(0);                                        \
    __builtin_amdgcn_s_setprio(1);                                            \
    _Pragma("unroll")                                                         \
    for (int ni = 0; ni < 4; ++ni) {                                          \
      const f16x8 bf = *(const f16x8*)(BsP + ((3 * (U) + (PH)) & 3) * 16384   \
                                       + b_base + ni * 1024);                 \
      acc[0][ni] = __builtin_amdgcn_mfma_f32_16x16x32_f16(af0, bf, acc[0][ni], 0, 0, 0); \
      acc[1][ni] = __builtin_amdgcn_mfma_f32_16x16x32_f16(af1, bf, acc[1][ni], 0, 0, 0); \
    }                                                                         \
    __builtin_amdgcn_s_setprio(0);                                            \
  }

#define SGBODY(U)                                                             \
  {                                                                           \
    const int sgp = 4 * B + (U) + 2;                                          \
    const int sgn = (sgp < NSG) ? sgp : (NSG - 1);                            \
    GRANP(U, 0, { })                                                          \
    GRANP(U, 1, { nx = xptr[8 * sgn]; })                                      \
    GRANP(U, 2, { })                                                          \
    cx = nx;                                                                  \
  }

  for (int B = 0; B < 16; ++B) {
    SGBODY(0)
    SGBODY(1)
    SGBODY(2)
    SGBODY(3)
  }
#undef SGBODY
#undef GRANP

  if (mode) {
    // partial-sum path: plain stores into part[s][b][j] (no atomics)
    float* pb = part + (size_t)blockIdx.x * OUT_ELEMS;
#pragma unroll
    for (int q = 0; q < 2; ++q) {
      const int gr = m0 + wm + q * 16 + fq * 4;
#pragma unroll
      for (int ni = 0; ni < 4; ++ni) {
        const int gc = wn + ni * 16 + fr;
#pragma unroll
        for (int r = 0; r < 4; ++r)
          pb[(size_t)(gr + r) * GNN + gc] = acc[q][ni][r];
      }
    }
  } else {
#pragma unroll
    for (int q = 0; q < 2; ++q) {
      const int gr = m0 + wm + q * 16 + fq * 4;
#pragma unroll
      for (int ni = 0; ni < 4; ++ni) {
        const int gc = wn + ni * 16 + fr;
#pragma unroll
        for (int r = 0; r < 4; ++r)
          atomicAdd(&out[(size_t)(gr + r) * GNN + gc], acc[q][ni][r]);
      }
    }
  }
}

// ================= fallback: direct dot2 path (no workspace) =================
#define TI 8
#define BT 256
#define JT 32
#define ISPL 2
#define IRANGE (1024 / ISPL)

__global__ __launch_bounds__(256)
void kan_dot2(const float* __restrict__ x, const float* __restrict__ coef,
              float* __restrict__ out) {
  __shared__ uint32_t Plds[TI * 12 * JT];
  const int t    = threadIdx.x;
  const int b    = blockIdx.x * BT + t;
  const int j0   = blockIdx.y * JT;
  const int cbeg = blockIdx.z * (IRANGE / TI);

  float acc[JT];
#pragma unroll
  for (int q = 0; q < JT; ++q) acc[q] = 0.0f;

  const int s_jj   = t & 31;
  const int s_iloc = t >> 5;

  for (int c = cbeg; c < cbeg + IRANGE / TI; ++c) {
    const int i0 = c * TI;
    __syncthreads();
    {
      const float* cp0 = coef + ((size_t)(j0 + s_jj) * 1024 + (i0 + s_iloc)) * 13;
      float cv[13];
#pragma unroll
      for (int s = 0; s < 13; ++s) cv[s] = cp0[s];
#pragma unroll
      for (int r = 0; r < 12; ++r) {
        half2_v h; h[0] = (_Float16)cv[r]; h[1] = (_Float16)cv[r + 1];
        const int slot = ((s_jj >> 2) + r) & 7;
        Plds[(s_iloc * 12 + r) * 32 + slot * 4 + (s_jj & 3)] = h2_as_u32(h);
      }
    }
    uint32_t wr[TI]; int lor[TI];
    {
      const float* xr = x + (size_t)b * 1024 + i0;
      const float4 xa = *(const float4*)(xr);
      const float4 xb = *(const float4*)(xr + 4);
      const float xv[TI] = {xa.x, xa.y, xa.z, xa.w, xb.x, xb.y, xb.z, xb.w};
#pragma unroll
      for (int q = 0; q < TI; ++q) {
        float w0, w1; int lo;
        kan_weights(xv[q], w0, w1, lo);
        wr[q] = (uint32_t)f16_bits(w0) | ((uint32_t)f16_bits(w1) << 16);
        lor[q] = lo;
      }
    }
    __syncthreads();

    const uint4* P4 = (const uint4*)Plds;
#pragma unroll
    for (int ii = 0; ii < TI; ++ii) {
      const half2_v hw = u32_as_h2(wr[ii]);
      const int lo = lor[ii];
      const int base = (ii * 12 + lo) * 8;
#pragma unroll
      for (int g = 0; g < 8; ++g) {
        const uint4 v = P4[base + ((g + lo) & 7)];
        acc[4 * g + 0] = dot2f(hw, u32_as_h2(v.x), acc[4 * g + 0]);
        acc[4 * g + 1] = dot2f(hw, u32_as_h2(v.y), acc[4 * g + 1]);
        acc[4 * g + 2] = dot2f(hw, u32_as_h2(v.z), acc[4 * g + 2]);
        acc[4 * g + 3] = dot2f(hw, u32_as_h2(v.w), acc[4 * g + 3]);
      }
    }
  }

  float* orow = out + (size_t)b * 256 + j0;
#pragma unroll
  for (int q = 0; q < JT; ++q) atomicAdd(orow + q, acc[q]);
}

extern "C" void kernel_launch(void* const* d_in, const int* in_sizes, int n_in,
                              void* d_out, int out_size, void* d_ws, size_t ws_size,
                              hipStream_t stream) {
  const float* x     = (const float*)d_in[0];
  const float* coef  = (const float*)d_in[1];
  float* out = (float*)d_out;

  const size_t b2_bytes   = (size_t)GNN * GK2 * 2;           // 6.29 MB
  const size_t part_off   = b2_bytes;                        // 16-B aligned
  const size_t part_bytes = (size_t)KSPL2 * OUT_ELEMS * 4;   // 16.8 MB

  if (ws_size >= part_off + part_bytes) {
    // no-atomic path: per-split partials + reduce
    _Float16* B2 = (_Float16*)d_ws;
    float* part  = (float*)((char*)d_ws + part_off);
    kan_prep_B2<<<512, 512, 0, stream>>>(coef, (uint32_t*)B2, (float4*)out, 0);
    dim3 grid(KSPL2, 1, GMM / BM2);                          // (2, 1, 128) = 256
    kan_gemm13<<<grid, 512, 0, stream>>>(x, B2, out, part, 1);
    kan_reduce2<<<OUT_ELEMS / 4 / 256, 256, 0, stream>>>((const float4*)part,
                                                         (float4*)out);
  } else if (ws_size >= b2_bytes) {
    // atomic path (16 MB of atomics)
    _Float16* B2 = (_Float16*)d_ws;
    kan_prep_B2<<<512, 512, 0, stream>>>(coef, (uint32_t*)B2, (float4*)out, 1);
    dim3 grid(KSPL2, 1, GMM / BM2);
    kan_gemm13<<<grid, 512, 0, stream>>>(x, B2, out, nullptr, 0);
  } else {
    (void)hipMemsetAsync(out, 0, (size_t)out_size * sizeof(float), stream);
    dim3 grid(8192 / BT, 256 / JT, ISPL);
    kan_dot2<<<grid, 256, 0, stream>>>(x, coef, out);
  }
}